// Round 7
// baseline (113.859 us; speedup 1.0000x reference)
//
#include <hip/hip_runtime.h>

typedef __attribute__((ext_vector_type(8))) short bf16x8;
typedef __attribute__((ext_vector_type(4))) float f32x4;

#define DD 64
#define SS 20
#define NPW 16            // nodes per wave = one MFMA M-tile
#define NPB 64            // nodes per block (4 waves)
#define CONVB 768         // conversion blocks embedded in the K2 dispatch

// swizzle: word index (0..63, 4B units) within a 256B X row; chunk(16B) ^= row&15
#define SWZ(u, w) ((((((w) >> 2)) ^ ((u) & 15)) << 2) | ((w) & 3))

__device__ __forceinline__ unsigned cvt_pk_bf16(float lo, float hi) {
    unsigned r;
    asm("v_cvt_pk_bf16_f32 %0, %1, %2" : "=v"(r) : "v"(lo), "v"(hi));
    return r;
}

// convert 16 floats / thread / iter (2x dwordx4 in flight per iter)
__device__ __forceinline__ void conv_body(const float* __restrict__ src,
                                          uint* __restrict__ dst,
                                          long n16, long tid0, long stride)
{
    const float4* s4 = (const float4*)src;
    uint4* d4 = (uint4*)dst;
    for (long i = tid0; i < n16; i += stride) {
        const float4 a = s4[4 * i + 0];
        const float4 b = s4[4 * i + 1];
        const float4 c = s4[4 * i + 2];
        const float4 d = s4[4 * i + 3];
        uint4 p, q;
        p.x = cvt_pk_bf16(a.x, a.y);  p.y = cvt_pk_bf16(a.z, a.w);
        p.z = cvt_pk_bf16(b.x, b.y);  p.w = cvt_pk_bf16(b.z, b.w);
        q.x = cvt_pk_bf16(c.x, c.y);  q.y = cvt_pk_bf16(c.z, c.w);
        q.z = cvt_pk_bf16(d.x, d.y);  q.w = cvt_pk_bf16(d.z, d.w);
        d4[2 * i + 0] = p;
        d4[2 * i + 1] = q;
    }
}

__global__ __launch_bounds__(256) void conv_bf16(const float* __restrict__ src,
                                                 uint* __restrict__ dst, long n16)
{
    conv_body(src, dst, n16,
              (long)blockIdx.x * blockDim.x + threadIdx.x,
              (long)gridDim.x * blockDim.x);
}

// Single-side gather+MFMA (R6-validated shape: 4 waves, 64 nodes, 32KB LDS).
// First `convb` blocks instead grid-stride-convert an independent table
// (conv_item overlaps gather_user: HBM-streaming vs L3-random — disjoint
// bottlenecks, hides ~13us of the serial conversion chain).
__global__ __launch_bounds__(256, 4) void sage_side(
    const int*  __restrict__ nodes, const int* __restrict__ nbrs,
    const uint* __restrict__ tb,
    const float* __restrict__ Ws, const float* __restrict__ bsp,
    const float* __restrict__ Wn, const float* __restrict__ bnp,
    float* __restrict__ o, int N,
    const float* __restrict__ csrc, uint* __restrict__ cdst, long cn16, int convb)
{
    __shared__ unsigned BP[16 * 64 * 4];   // 16 B-frags x 64 lanes x 16B = 16 KB
    __shared__ unsigned XW[4][NPW][64];    // per-wave bf16 X tile, swizzled: 16 KB

    const int tid = threadIdx.x;

    if ((int)blockIdx.x < convb) {         // embedded overlap conversion
        conv_body(csrc, cdst, cn16,
                  (long)blockIdx.x * 256 + tid, (long)convb * 256);
        return;
    }
    const int blk = (int)blockIdx.x - convb;

    const int lane   = tid & 63;
    const int wid    = tid >> 6;
    const int lane15 = lane & 15;
    const int grp    = lane >> 4;

    // ---- Phase 0: W2^T -> bf16 B-fragments in LDS ----
    // frag(t,c): lane l holds B[k = t*32 + (l>>4)*8 + i][n = c*16 + (l&15)],
    // B[k][n] = W2[n][k] (Ws for k<64, Wn for k>=64).
    #pragma unroll
    for (int it = 0; it < 4; ++it) {
        const int fid = it * 4 + wid;          // 0..15, wave-uniform
        const int t = fid >> 2, c = fid & 3;
        const int n  = c * 16 + lane15;
        const int kb = t * 32 + (grp << 3);
        const float* src = (kb < 64) ? (Ws + n * 64 + kb) : (Wn + n * 64 + (kb - 64));
        const float4 v0 = *(const float4*)(src);
        const float4 v1 = *(const float4*)(src + 4);
        uint4 p;
        p.x = cvt_pk_bf16(v0.x, v0.y);
        p.y = cvt_pk_bf16(v0.z, v0.w);
        p.z = cvt_pk_bf16(v1.x, v1.y);
        p.w = cvt_pk_bf16(v1.z, v1.w);
        *(uint4*)&BP[(fid * 64 + lane) * 4] = p;
    }

    float bcol[4];
    #pragma unroll
    for (int c = 0; c < 4; ++c) {
        const int col = c * 16 + lane15;
        bcol[c] = bsp[col] + bnp[col];
    }
    __syncthreads();

    const int n0 = blk * NPB + wid * NPW;
    if (n0 >= N) return;   // whole-wave tail guard (no barriers below)

    // self indices for this wave's 16 nodes, staged in lanes 0..15
    const int nd = nodes[min(n0 + lane15, N - 1)];

    // ---- gather 16 nodes in 4 sub-batches of 4 ----
    #pragma unroll
    for (int sb = 0; sb < 4; ++sb) {
        const int u  = sb * 4 + grp;                 // node owned by this group
        const int nn = min(n0 + u, N - 1);

        // neighbor indices of node nn staged across this group's 16 lanes
        const int  nb0 = nbrs[(size_t)nn * SS + lane15];                 // s=0..15
        const long f1  = min((long)nn * SS + 16 + lane15, (long)N * SS - 1);
        const int  nb1 = nbrs[f1];                                       // s=16..19

        // self row: raw bf16 bits, dims 4m..4m+3 in lane m of the group
        const int sidx = __shfl(nd, u, 64);
        const uint2 sv = ((const uint2*)(tb + (size_t)sidx * 32))[lane15];

        float a0 = 0.f, a1 = 0.f, a2 = 0.f, a3 = 0.f;
        #pragma unroll
        for (int b = 0; b < SS; ++b) {
            const int idx = (b < 16) ? __shfl(nb0, (lane & 48) | b, 64)
                                     : __shfl(nb1, (lane & 48) | (b - 16), 64);
            const uint2 r = ((const uint2*)(tb + (size_t)idx * 32))[lane15];
            a0 += __uint_as_float(r.x << 16);
            a1 += __uint_as_float(r.x & 0xffff0000u);
            a2 += __uint_as_float(r.y << 16);
            a3 += __uint_as_float(r.y & 0xffff0000u);
        }
        const float is = 1.0f / SS;

        const int m = lane15;
        uint2 pagg;
        pagg.x = cvt_pk_bf16(a0 * is, a1 * is);
        pagg.y = cvt_pk_bf16(a2 * is, a3 * is);
        *(uint2*)&XW[wid][u][SWZ(u, 2 * m)]      = sv;      // k = 4m..4m+3
        *(uint2*)&XW[wid][u][SWZ(u, 32 + 2 * m)] = pagg;    // k = 64+4m..
    }
    // XW written & read by the same wave -> lgkmcnt dependence, no barrier.

    // ---- MFMA: M=16, N=64, K=128 ----
    union AB { uint4 u4; bf16x8 v; };
    const f32x4 zero = {0.f, 0.f, 0.f, 0.f};
    f32x4 acc[4] = {zero, zero, zero, zero};
    #pragma unroll
    for (int t = 0; t < 4; ++t) {
        const int r     = lane15;
        const int chunk = t * 4 + grp;               // k = chunk*8
        AB a;
        a.u4 = *(const uint4*)&XW[wid][r][((chunk ^ r) << 2)];
        #pragma unroll
        for (int c = 0; c < 4; ++c) {
            AB b;
            b.u4 = *(const uint4*)&BP[((t * 4 + c) * 64 + lane) * 4];
            acc[c] = __builtin_amdgcn_mfma_f32_16x16x32_bf16(a.v, b.v, acc[c], 0, 0, 0);
        }
    }

    // ---- Epilogue: bias, relu, row-norm (16-lane-group reduce), store ----
    float rl[4][4];
    float ssq[4] = {0.f, 0.f, 0.f, 0.f};
    #pragma unroll
    for (int c = 0; c < 4; ++c) {
        #pragma unroll
        for (int j = 0; j < 4; ++j) {
            const float v = fmaxf(acc[c][j] + bcol[c], 0.f);
            rl[c][j] = v;
            ssq[j] = fmaf(v, v, ssq[j]);
        }
    }
    #pragma unroll
    for (int j = 0; j < 4; ++j) {
        #pragma unroll
        for (int m = 1; m < 16; m <<= 1)
            ssq[j] += __shfl_xor(ssq[j], m, 64);
    }
    float inv[4];
    #pragma unroll
    for (int j = 0; j < 4; ++j)
        inv[j] = 1.0f / fmaxf(sqrtf(ssq[j]), 1e-12f);

    #pragma unroll
    for (int j = 0; j < 4; ++j) {
        const int row = (grp << 2) + j;              // C/D: row=(l>>4)*4+reg
        const int ni  = n0 + row;
        if (ni < N) {
            #pragma unroll
            for (int c = 0; c < 4; ++c)
                o[(size_t)ni * DD + c * 16 + lane15] = rl[c][j] * inv[j];
        }
    }
}

// ---- fallback (R4 fp32-gather path) if d_ws can't hold the bf16 tables ----
__global__ __launch_bounds__(256, 4) void sage_fp32(
    const int*   __restrict__ u_nodes, const int* __restrict__ i_nodes,
    const int*   __restrict__ u_nbrs,  const int* __restrict__ i_nbrs,
    const float* __restrict__ u_table, const float* __restrict__ i_table,
    const float* __restrict__ Wsu, const float* __restrict__ bsu,
    const float* __restrict__ Wnu, const float* __restrict__ bnu,
    const float* __restrict__ Wsi, const float* __restrict__ bsi,
    const float* __restrict__ Wni, const float* __restrict__ bni,
    float* __restrict__ out, int N, int nblk_side)
{
    __shared__ unsigned BP[16 * 64 * 4];
    __shared__ unsigned XW[4][NPW][64];

    const int tid    = threadIdx.x;
    const int lane   = tid & 63;
    const int wid    = tid >> 6;
    const int lane15 = lane & 15;
    const int grp    = lane >> 4;

    const bool item_side = (int)blockIdx.x >= nblk_side;
    const int  blk = item_side ? (int)blockIdx.x - nblk_side : (int)blockIdx.x;

    const int*   nodes = item_side ? i_nodes : u_nodes;
    const int*   nbrs  = item_side ? i_nbrs  : u_nbrs;
    const float* table = item_side ? i_table : u_table;
    const float* Ws    = item_side ? Wsi : Wsu;
    const float* bsp   = item_side ? bsi : bsu;
    const float* Wn    = item_side ? Wni : Wnu;
    const float* bnp   = item_side ? bni : bnu;
    float* o = out + (item_side ? (size_t)N * DD : 0);

    #pragma unroll
    for (int it = 0; it < 4; ++it) {
        const int fid = it * 4 + wid;
        const int t = fid >> 2, c = fid & 3;
        const int n  = c * 16 + lane15;
        const int kb = t * 32 + (grp << 3);
        const float* src = (kb < 64) ? (Ws + n * 64 + kb) : (Wn + n * 64 + (kb - 64));
        const float4 v0 = *(const float4*)(src);
        const float4 v1 = *(const float4*)(src + 4);
        uint4 p;
        p.x = cvt_pk_bf16(v0.x, v0.y);
        p.y = cvt_pk_bf16(v0.z, v0.w);
        p.z = cvt_pk_bf16(v1.x, v1.y);
        p.w = cvt_pk_bf16(v1.z, v1.w);
        *(uint4*)&BP[(fid * 64 + lane) * 4] = p;
    }

    float bcol[4];
    #pragma unroll
    for (int c = 0; c < 4; ++c) bcol[c] = bsp[c * 16 + lane15] + bnp[c * 16 + lane15];
    __syncthreads();

    const int n0 = blk * NPB + wid * NPW;
    if (n0 >= N) return;

    const int nd = nodes[min(n0 + lane15, N - 1)];

    #pragma unroll
    for (int sb = 0; sb < 4; ++sb) {
        const int u  = sb * 4 + grp;
        const int nn = min(n0 + u, N - 1);
        const int  nb0 = nbrs[(size_t)nn * SS + lane15];
        const long f1  = min((long)nn * SS + 16 + lane15, (long)N * SS - 1);
        const int  nb1 = nbrs[f1];
        const int sidx = __shfl(nd, u, 64);
        const float4 self4 = ((const float4*)(table + (size_t)sidx * DD))[lane15];
        float4 agg = {0.f, 0.f, 0.f, 0.f};
        #pragma unroll
        for (int b = 0; b < SS; ++b) {
            const int idx = (b < 16) ? __shfl(nb0, (lane & 48) | b, 64)
                                     : __shfl(nb1, (lane & 48) | (b - 16), 64);
            const float4 r4 = ((const float4*)(table + (size_t)idx * DD))[lane15];
            agg.x += r4.x; agg.y += r4.y; agg.z += r4.z; agg.w += r4.w;
        }
        const float is = 1.0f / SS;
        const int m = lane15;
        uint2 pself, pagg;
        pself.x = cvt_pk_bf16(self4.x, self4.y);
        pself.y = cvt_pk_bf16(self4.z, self4.w);
        pagg.x  = cvt_pk_bf16(agg.x * is, agg.y * is);
        pagg.y  = cvt_pk_bf16(agg.z * is, agg.w * is);
        *(uint2*)&XW[wid][u][SWZ(u, 2 * m)]      = pself;
        *(uint2*)&XW[wid][u][SWZ(u, 32 + 2 * m)] = pagg;
    }

    union AB { uint4 u4; bf16x8 v; };
    const f32x4 zero = {0.f, 0.f, 0.f, 0.f};
    f32x4 acc[4] = {zero, zero, zero, zero};
    #pragma unroll
    for (int t = 0; t < 4; ++t) {
        const int r     = lane15;
        const int chunk = t * 4 + grp;
        AB a;
        a.u4 = *(const uint4*)&XW[wid][r][((chunk ^ r) << 2)];
        #pragma unroll
        for (int c = 0; c < 4; ++c) {
            AB b;
            b.u4 = *(const uint4*)&BP[((t * 4 + c) * 64 + lane) * 4];
            acc[c] = __builtin_amdgcn_mfma_f32_16x16x32_bf16(a.v, b.v, acc[c], 0, 0, 0);
        }
    }

    float rl[4][4];
    float ssq[4] = {0.f, 0.f, 0.f, 0.f};
    #pragma unroll
    for (int c = 0; c < 4; ++c) {
        #pragma unroll
        for (int j = 0; j < 4; ++j) {
            const float v = fmaxf(acc[c][j] + bcol[c], 0.f);
            rl[c][j] = v;
            ssq[j] = fmaf(v, v, ssq[j]);
        }
    }
    #pragma unroll
    for (int j = 0; j < 4; ++j) {
        #pragma unroll
        for (int m = 1; m < 16; m <<= 1) ssq[j] += __shfl_xor(ssq[j], m, 64);
    }
    float inv[4];
    #pragma unroll
    for (int j = 0; j < 4; ++j) inv[j] = 1.0f / fmaxf(sqrtf(ssq[j]), 1e-12f);
    #pragma unroll
    for (int j = 0; j < 4; ++j) {
        const int row = (grp << 2) + j;
        const int ni  = n0 + row;
        if (ni < N) {
            #pragma unroll
            for (int c = 0; c < 4; ++c)
                o[(size_t)ni * DD + c * 16 + lane15] = rl[c][j] * inv[j];
        }
    }
}

extern "C" void kernel_launch(void* const* d_in, const int* in_sizes, int n_in,
                              void* d_out, int out_size, void* d_ws, size_t ws_size,
                              hipStream_t stream) {
    const int*   user_nodes = (const int*)  d_in[0];
    const int*   item_nodes = (const int*)  d_in[1];
    const int*   user_nbrs  = (const int*)  d_in[2];
    const int*   item_nbrs  = (const int*)  d_in[3];
    const float* user_table = (const float*)d_in[4];
    const float* item_table = (const float*)d_in[5];
    const float* Wsu = (const float*)d_in[6];
    const float* bsu = (const float*)d_in[7];
    const float* Wnu = (const float*)d_in[8];
    const float* bnu = (const float*)d_in[9];
    const float* Wsi = (const float*)d_in[10];
    const float* bsi = (const float*)d_in[11];
    const float* Wni = (const float*)d_in[12];
    const float* bni = (const float*)d_in[13];

    float* out = (float*)d_out;
    const int N = in_sizes[0];
    const int nblk_side = (N + NPB - 1) / NPB;

    const long nu = in_sizes[4];   // user_table elements
    const long ni = in_sizes[5];   // item_table elements
    const size_t need = (size_t)(nu + ni) * 2;   // bf16 bytes

    if (ws_size >= need) {
        uint* u_tb = (uint*)d_ws;
        uint* i_tb = u_tb + (nu >> 1);   // nu bf16 = nu/2 uints

        // K1: convert user table (serial head, ~13us, HBM roofline)
        conv_bf16<<<1024, 256, 0, stream>>>(user_table, u_tb, nu >> 4);

        // K2: gather user side, overlapped with item-table conversion
        sage_side<<<CONVB + nblk_side, 256, 0, stream>>>(
            user_nodes, user_nbrs, (const uint*)u_tb,
            Wsu, bsu, Wnu, bnu, out, N,
            item_table, i_tb, ni >> 4, CONVB);

        // K3: gather item side
        sage_side<<<nblk_side, 256, 0, stream>>>(
            item_nodes, item_nbrs, (const uint*)i_tb,
            Wsi, bsi, Wni, bni, out + (size_t)N * DD, N,
            nullptr, nullptr, 0, 0);
    } else {
        sage_fp32<<<2 * nblk_side, 256, 0, stream>>>(
            user_nodes, item_nodes, user_nbrs, item_nbrs,
            user_table, item_table,
            Wsu, bsu, Wnu, bnu, Wsi, bsi, Wni, bni,
            out, N, nblk_side);
    }
}

// Round 8
// 108.051 us; speedup vs baseline: 1.0537x; 1.0537x over previous
//
#include <hip/hip_runtime.h>

typedef __attribute__((ext_vector_type(8))) short bf16x8;
typedef __attribute__((ext_vector_type(4))) float f32x4;

#define DD 64
#define SS 20
#define NPW 16            // nodes per wave = one MFMA M-tile
#define NPB 64            // nodes per block (4 waves)

// swizzle: word index (0..63, 4B units) within a 256B X row; chunk(16B) ^= row&15
#define SWZ(u, w) ((((((w) >> 2)) ^ ((u) & 15)) << 2) | ((w) & 3))

__device__ __forceinline__ unsigned cvt_pk_bf16(float lo, float hi) {
    unsigned r;
    asm("v_cvt_pk_bf16_f32 %0, %1, %2" : "=v"(r) : "v"(lo), "v"(hi));
    return r;
}

// convert 16 floats / thread / iter (2x dwordx4 in flight per iter)
__device__ __forceinline__ void conv_body(const float* __restrict__ src,
                                          uint* __restrict__ dst,
                                          long n16, long tid0, long stride)
{
    const float4* s4 = (const float4*)src;
    uint4* d4 = (uint4*)dst;
    for (long i = tid0; i < n16; i += stride) {
        const float4 a = s4[4 * i + 0];
        const float4 b = s4[4 * i + 1];
        const float4 c = s4[4 * i + 2];
        const float4 d = s4[4 * i + 3];
        uint4 p, q;
        p.x = cvt_pk_bf16(a.x, a.y);  p.y = cvt_pk_bf16(a.z, a.w);
        p.z = cvt_pk_bf16(b.x, b.y);  p.w = cvt_pk_bf16(b.z, b.w);
        q.x = cvt_pk_bf16(c.x, c.y);  q.y = cvt_pk_bf16(c.z, c.w);
        q.z = cvt_pk_bf16(d.x, d.y);  q.w = cvt_pk_bf16(d.z, d.w);
        d4[2 * i + 0] = p;
        d4[2 * i + 1] = q;
    }
}

// Both tables in one dispatch: first half of blocks convert the user table,
// second half the item table (removes one dispatch drain vs two launches).
__global__ __launch_bounds__(256) void conv_both(
    const float* __restrict__ usrc, uint* __restrict__ udst, long un16,
    const float* __restrict__ isrc, uint* __restrict__ idst, long in16,
    int half_blocks)
{
    if ((int)blockIdx.x < half_blocks) {
        conv_body(usrc, udst, un16,
                  (long)blockIdx.x * blockDim.x + threadIdx.x,
                  (long)half_blocks * blockDim.x);
    } else {
        conv_body(isrc, idst, in16,
                  (long)(blockIdx.x - half_blocks) * blockDim.x + threadIdx.x,
                  (long)half_blocks * blockDim.x);
    }
}

// Combined dual-side gather+MFMA (R6-validated best: 4 waves, 64 nodes/block,
// 32KB LDS, ~3.5 TB/s EA = path roofline for random 128B bf16 rows).
__global__ __launch_bounds__(256, 4) void sage_bf16(
    const int*  __restrict__ u_nodes, const int* __restrict__ i_nodes,
    const int*  __restrict__ u_nbrs,  const int* __restrict__ i_nbrs,
    const uint* __restrict__ u_tb,    const uint* __restrict__ i_tb,
    const float* __restrict__ Wsu, const float* __restrict__ bsu,
    const float* __restrict__ Wnu, const float* __restrict__ bnu,
    const float* __restrict__ Wsi, const float* __restrict__ bsi,
    const float* __restrict__ Wni, const float* __restrict__ bni,
    float* __restrict__ out, int N, int nblk_side)
{
    __shared__ unsigned BP[16 * 64 * 4];   // 16 B-frags x 64 lanes x 16B = 16 KB
    __shared__ unsigned XW[4][NPW][64];    // per-wave bf16 X tile, swizzled: 16 KB

    const int tid    = threadIdx.x;
    const int lane   = tid & 63;
    const int wid    = tid >> 6;
    const int lane15 = lane & 15;
    const int grp    = lane >> 4;

    const bool item_side = (int)blockIdx.x >= nblk_side;
    const int  blk = item_side ? (int)blockIdx.x - nblk_side : (int)blockIdx.x;

    const int*  nodes = item_side ? i_nodes : u_nodes;
    const int*  nbrs  = item_side ? i_nbrs  : u_nbrs;
    const uint* tb    = item_side ? i_tb    : u_tb;     // bf16 rows, 32 uints each
    const float* Ws   = item_side ? Wsi : Wsu;
    const float* bsp  = item_side ? bsi : bsu;
    const float* Wn   = item_side ? Wni : Wnu;
    const float* bnp  = item_side ? bni : bnu;
    float* o = out + (item_side ? (size_t)N * DD : 0);

    // ---- Phase 0: W2^T -> bf16 B-fragments in LDS ----
    // frag(t,c): lane l holds B[k = t*32 + (l>>4)*8 + i][n = c*16 + (l&15)],
    // B[k][n] = W2[n][k] (Ws for k<64, Wn for k>=64).
    #pragma unroll
    for (int it = 0; it < 4; ++it) {
        const int fid = it * 4 + wid;          // 0..15, wave-uniform
        const int t = fid >> 2, c = fid & 3;
        const int n  = c * 16 + lane15;
        const int kb = t * 32 + (grp << 3);
        const float* src = (kb < 64) ? (Ws + n * 64 + kb) : (Wn + n * 64 + (kb - 64));
        const float4 v0 = *(const float4*)(src);
        const float4 v1 = *(const float4*)(src + 4);
        uint4 p;
        p.x = cvt_pk_bf16(v0.x, v0.y);
        p.y = cvt_pk_bf16(v0.z, v0.w);
        p.z = cvt_pk_bf16(v1.x, v1.y);
        p.w = cvt_pk_bf16(v1.z, v1.w);
        *(uint4*)&BP[(fid * 64 + lane) * 4] = p;
    }

    float bcol[4];
    #pragma unroll
    for (int c = 0; c < 4; ++c) {
        const int col = c * 16 + lane15;
        bcol[c] = bsp[col] + bnp[col];
    }
    __syncthreads();

    const int n0 = blk * NPB + wid * NPW;
    if (n0 >= N) return;   // whole-wave tail guard (no barriers below)

    // self indices for this wave's 16 nodes, staged in lanes 0..15
    const int nd = nodes[min(n0 + lane15, N - 1)];

    // ---- gather 16 nodes in 4 sub-batches of 4 ----
    #pragma unroll
    for (int sb = 0; sb < 4; ++sb) {
        const int u  = sb * 4 + grp;                 // node owned by this group
        const int nn = min(n0 + u, N - 1);

        // neighbor indices of node nn staged across this group's 16 lanes
        const int  nb0 = nbrs[(size_t)nn * SS + lane15];                 // s=0..15
        const long f1  = min((long)nn * SS + 16 + lane15, (long)N * SS - 1);
        const int  nb1 = nbrs[f1];                                       // s=16..19

        // self row: raw bf16 bits, dims 4m..4m+3 in lane m of the group
        const int sidx = __shfl(nd, u, 64);
        const uint2 sv = ((const uint2*)(tb + (size_t)sidx * 32))[lane15];

        float a0 = 0.f, a1 = 0.f, a2 = 0.f, a3 = 0.f;
        #pragma unroll
        for (int b = 0; b < SS; ++b) {
            const int idx = (b < 16) ? __shfl(nb0, (lane & 48) | b, 64)
                                     : __shfl(nb1, (lane & 48) | (b - 16), 64);
            const uint2 r = ((const uint2*)(tb + (size_t)idx * 32))[lane15];
            a0 += __uint_as_float(r.x << 16);
            a1 += __uint_as_float(r.x & 0xffff0000u);
            a2 += __uint_as_float(r.y << 16);
            a3 += __uint_as_float(r.y & 0xffff0000u);
        }
        const float is = 1.0f / SS;

        const int m = lane15;
        uint2 pagg;
        pagg.x = cvt_pk_bf16(a0 * is, a1 * is);
        pagg.y = cvt_pk_bf16(a2 * is, a3 * is);
        *(uint2*)&XW[wid][u][SWZ(u, 2 * m)]      = sv;      // k = 4m..4m+3
        *(uint2*)&XW[wid][u][SWZ(u, 32 + 2 * m)] = pagg;    // k = 64+4m..
    }
    // XW written & read by the same wave -> lgkmcnt dependence, no barrier.

    // ---- MFMA: M=16, N=64, K=128 ----
    union AB { uint4 u4; bf16x8 v; };
    const f32x4 zero = {0.f, 0.f, 0.f, 0.f};
    f32x4 acc[4] = {zero, zero, zero, zero};
    #pragma unroll
    for (int t = 0; t < 4; ++t) {
        const int r     = lane15;
        const int chunk = t * 4 + grp;               // k = chunk*8
        AB a;
        a.u4 = *(const uint4*)&XW[wid][r][((chunk ^ r) << 2)];
        #pragma unroll
        for (int c = 0; c < 4; ++c) {
            AB b;
            b.u4 = *(const uint4*)&BP[((t * 4 + c) * 64 + lane) * 4];
            acc[c] = __builtin_amdgcn_mfma_f32_16x16x32_bf16(a.v, b.v, acc[c], 0, 0, 0);
        }
    }

    // ---- Epilogue: bias, relu, row-norm (16-lane-group reduce), store ----
    float rl[4][4];
    float ssq[4] = {0.f, 0.f, 0.f, 0.f};
    #pragma unroll
    for (int c = 0; c < 4; ++c) {
        #pragma unroll
        for (int j = 0; j < 4; ++j) {
            const float v = fmaxf(acc[c][j] + bcol[c], 0.f);
            rl[c][j] = v;
            ssq[j] = fmaf(v, v, ssq[j]);
        }
    }
    #pragma unroll
    for (int j = 0; j < 4; ++j) {
        #pragma unroll
        for (int m = 1; m < 16; m <<= 1)
            ssq[j] += __shfl_xor(ssq[j], m, 64);
    }
    float inv[4];
    #pragma unroll
    for (int j = 0; j < 4; ++j)
        inv[j] = 1.0f / fmaxf(sqrtf(ssq[j]), 1e-12f);

    #pragma unroll
    for (int j = 0; j < 4; ++j) {
        const int row = (grp << 2) + j;              // C/D: row=(l>>4)*4+reg
        const int ni  = n0 + row;
        if (ni < N) {
            #pragma unroll
            for (int c = 0; c < 4; ++c)
                o[(size_t)ni * DD + c * 16 + lane15] = rl[c][j] * inv[j];
        }
    }
}

// ---- fallback (fp32-gather path) if d_ws can't hold the bf16 tables ----
__global__ __launch_bounds__(256, 4) void sage_fp32(
    const int*   __restrict__ u_nodes, const int* __restrict__ i_nodes,
    const int*   __restrict__ u_nbrs,  const int* __restrict__ i_nbrs,
    const float* __restrict__ u_table, const float* __restrict__ i_table,
    const float* __restrict__ Wsu, const float* __restrict__ bsu,
    const float* __restrict__ Wnu, const float* __restrict__ bnu,
    const float* __restrict__ Wsi, const float* __restrict__ bsi,
    const float* __restrict__ Wni, const float* __restrict__ bni,
    float* __restrict__ out, int N, int nblk_side)
{
    __shared__ unsigned BP[16 * 64 * 4];
    __shared__ unsigned XW[4][NPW][64];

    const int tid    = threadIdx.x;
    const int lane   = tid & 63;
    const int wid    = tid >> 6;
    const int lane15 = lane & 15;
    const int grp    = lane >> 4;

    const bool item_side = (int)blockIdx.x >= nblk_side;
    const int  blk = item_side ? (int)blockIdx.x - nblk_side : (int)blockIdx.x;

    const int*   nodes = item_side ? i_nodes : u_nodes;
    const int*   nbrs  = item_side ? i_nbrs  : u_nbrs;
    const float* table = item_side ? i_table : u_table;
    const float* Ws    = item_side ? Wsi : Wsu;
    const float* bsp   = item_side ? bsi : bsu;
    const float* Wn    = item_side ? Wni : Wnu;
    const float* bnp   = item_side ? bni : bnu;
    float* o = out + (item_side ? (size_t)N * DD : 0);

    #pragma unroll
    for (int it = 0; it < 4; ++it) {
        const int fid = it * 4 + wid;
        const int t = fid >> 2, c = fid & 3;
        const int n  = c * 16 + lane15;
        const int kb = t * 32 + (grp << 3);
        const float* src = (kb < 64) ? (Ws + n * 64 + kb) : (Wn + n * 64 + (kb - 64));
        const float4 v0 = *(const float4*)(src);
        const float4 v1 = *(const float4*)(src + 4);
        uint4 p;
        p.x = cvt_pk_bf16(v0.x, v0.y);
        p.y = cvt_pk_bf16(v0.z, v0.w);
        p.z = cvt_pk_bf16(v1.x, v1.y);
        p.w = cvt_pk_bf16(v1.z, v1.w);
        *(uint4*)&BP[(fid * 64 + lane) * 4] = p;
    }

    float bcol[4];
    #pragma unroll
    for (int c = 0; c < 4; ++c) bcol[c] = bsp[c * 16 + lane15] + bnp[c * 16 + lane15];
    __syncthreads();

    const int n0 = blk * NPB + wid * NPW;
    if (n0 >= N) return;

    const int nd = nodes[min(n0 + lane15, N - 1)];

    #pragma unroll
    for (int sb = 0; sb < 4; ++sb) {
        const int u  = sb * 4 + grp;
        const int nn = min(n0 + u, N - 1);
        const int  nb0 = nbrs[(size_t)nn * SS + lane15];
        const long f1  = min((long)nn * SS + 16 + lane15, (long)N * SS - 1);
        const int  nb1 = nbrs[f1];
        const int sidx = __shfl(nd, u, 64);
        const float4 self4 = ((const float4*)(table + (size_t)sidx * DD))[lane15];
        float4 agg = {0.f, 0.f, 0.f, 0.f};
        #pragma unroll
        for (int b = 0; b < SS; ++b) {
            const int idx = (b < 16) ? __shfl(nb0, (lane & 48) | b, 64)
                                     : __shfl(nb1, (lane & 48) | (b - 16), 64);
            const float4 r4 = ((const float4*)(table + (size_t)idx * DD))[lane15];
            agg.x += r4.x; agg.y += r4.y; agg.z += r4.z; agg.w += r4.w;
        }
        const float is = 1.0f / SS;
        const int m = lane15;
        uint2 pself, pagg;
        pself.x = cvt_pk_bf16(self4.x, self4.y);
        pself.y = cvt_pk_bf16(self4.z, self4.w);
        pagg.x  = cvt_pk_bf16(agg.x * is, agg.y * is);
        pagg.y  = cvt_pk_bf16(agg.z * is, agg.w * is);
        *(uint2*)&XW[wid][u][SWZ(u, 2 * m)]      = pself;
        *(uint2*)&XW[wid][u][SWZ(u, 32 + 2 * m)] = pagg;
    }

    union AB { uint4 u4; bf16x8 v; };
    const f32x4 zero = {0.f, 0.f, 0.f, 0.f};
    f32x4 acc[4] = {zero, zero, zero, zero};
    #pragma unroll
    for (int t = 0; t < 4; ++t) {
        const int r     = lane15;
        const int chunk = t * 4 + grp;
        AB a;
        a.u4 = *(const uint4*)&XW[wid][r][((chunk ^ r) << 2)];
        #pragma unroll
        for (int c = 0; c < 4; ++c) {
            AB b;
            b.u4 = *(const uint4*)&BP[((t * 4 + c) * 64 + lane) * 4];
            acc[c] = __builtin_amdgcn_mfma_f32_16x16x32_bf16(a.v, b.v, acc[c], 0, 0, 0);
        }
    }

    float rl[4][4];
    float ssq[4] = {0.f, 0.f, 0.f, 0.f};
    #pragma unroll
    for (int c = 0; c < 4; ++c) {
        #pragma unroll
        for (int j = 0; j < 4; ++j) {
            const float v = fmaxf(acc[c][j] + bcol[c], 0.f);
            rl[c][j] = v;
            ssq[j] = fmaf(v, v, ssq[j]);
        }
    }
    #pragma unroll
    for (int j = 0; j < 4; ++j) {
        #pragma unroll
        for (int m = 1; m < 16; m <<= 1) ssq[j] += __shfl_xor(ssq[j], m, 64);
    }
    float inv[4];
    #pragma unroll
    for (int j = 0; j < 4; ++j) inv[j] = 1.0f / fmaxf(sqrtf(ssq[j]), 1e-12f);
    #pragma unroll
    for (int j = 0; j < 4; ++j) {
        const int row = (grp << 2) + j;
        const int ni  = n0 + row;
        if (ni < N) {
            #pragma unroll
            for (int c = 0; c < 4; ++c)
                o[(size_t)ni * DD + c * 16 + lane15] = rl[c][j] * inv[j];
        }
    }
}

extern "C" void kernel_launch(void* const* d_in, const int* in_sizes, int n_in,
                              void* d_out, int out_size, void* d_ws, size_t ws_size,
                              hipStream_t stream) {
    const int*   user_nodes = (const int*)  d_in[0];
    const int*   item_nodes = (const int*)  d_in[1];
    const int*   user_nbrs  = (const int*)  d_in[2];
    const int*   item_nbrs  = (const int*)  d_in[3];
    const float* user_table = (const float*)d_in[4];
    const float* item_table = (const float*)d_in[5];
    const float* Wsu = (const float*)d_in[6];
    const float* bsu = (const float*)d_in[7];
    const float* Wnu = (const float*)d_in[8];
    const float* bnu = (const float*)d_in[9];
    const float* Wsi = (const float*)d_in[10];
    const float* bsi = (const float*)d_in[11];
    const float* Wni = (const float*)d_in[12];
    const float* bni = (const float*)d_in[13];

    float* out = (float*)d_out;
    const int N = in_sizes[0];
    const int nblk_side = (N + NPB - 1) / NPB;

    const long nu = in_sizes[4];   // user_table elements
    const long ni = in_sizes[5];   // item_table elements
    const size_t need = (size_t)(nu + ni) * 2;   // bf16 bytes

    if (ws_size >= need) {
        uint* u_tb = (uint*)d_ws;
        uint* i_tb = u_tb + (nu >> 1);   // nu bf16 = nu/2 uints

        // K1: convert both tables in one dispatch (~23us, HBM-stream bound)
        conv_both<<<2048, 256, 0, stream>>>(user_table, u_tb, nu >> 4,
                                            item_table, i_tb, ni >> 4, 1024);

        // K2: combined dual-side gather+MFMA (~83us @ ~3.5 TB/s EA roofline)
        sage_bf16<<<2 * nblk_side, 256, 0, stream>>>(
            user_nodes, item_nodes, user_nbrs, item_nbrs,
            (const uint*)u_tb, (const uint*)i_tb,
            Wsu, bsu, Wnu, bnu, Wsi, bsi, Wni, bni,
            out, N, nblk_side);
    } else {
        sage_fp32<<<2 * nblk_side, 256, 0, stream>>>(
            user_nodes, item_nodes, user_nbrs, item_nbrs,
            user_table, item_table,
            Wsu, bsu, Wnu, bnu, Wsi, bsi, Wni, bni,
            out, N, nblk_side);
    }
}